// Round 12
// baseline (445.375 us; speedup 1.0000x reference)
//
#include <hip/hip_runtime.h>

#define NN 20000
#define NE 300000

typedef unsigned short u16;
typedef unsigned int   u32;

typedef __bf16 bf16x8 __attribute__((ext_vector_type(8)));
typedef float  f32x4  __attribute__((ext_vector_type(4)));

__device__ __forceinline__ float b2f(u16 u){ u32 x = ((u32)u) << 16; return __builtin_bit_cast(float, x); }
__device__ __forceinline__ u16 f2b(float f){
    u32 x = __builtin_bit_cast(u32, f);
    u32 r = x + 0x7fffu + ((x >> 16) & 1u);
    return (u16)(r >> 16);
}

// ---------------- CSR build: bucket edges by col (target), store row (source) ----------------
__global__ void k_count(const int* __restrict__ key, int* __restrict__ deg){
    int e = blockIdx.x * 256 + threadIdx.x;
    if (e < NE){
        int c = key[e];
        if (c >= 0 && c < NN) atomicAdd(&deg[c], 1);
    }
}

__global__ void k_scan(const int* __restrict__ deg, int* __restrict__ offs, float* __restrict__ invd){
    __shared__ int part[1024];
    int t = threadIdx.x;
    int base = t * 20;
    int s = 0;
    for (int i = 0; i < 20; i++){ int idx = base + i; if (idx < NN) s += deg[idx]; }
    part[t] = s; __syncthreads();
    for (int d = 1; d < 1024; d <<= 1){
        int v = (t >= d) ? part[t - d] : 0;
        __syncthreads();
        part[t] += v;
        __syncthreads();
    }
    int run = part[t] - s;
    for (int i = 0; i < 20; i++){
        int idx = base + i;
        if (idx < NN){
            offs[idx] = run;
            int d0 = deg[idx];
            run += d0;
            invd[idx] = 1.0f / (float)(d0 > 0 ? d0 : 1);
        }
    }
    if (t == 1023) offs[NN] = part[1023];
}

__global__ void k_fill(const int* __restrict__ val, const int* __restrict__ key,
                       const int* __restrict__ offs, int* __restrict__ cur, int* __restrict__ srcs){
    int e = blockIdx.x * 256 + threadIdx.x;
    if (e < NE){
        int c = key[e];
        if (c >= 0 && c < NN){
            int slot = offs[c] + atomicAdd(&cur[c], 1);
            int r = val[e];
            srcs[slot] = (r >= 0 && r < NN) ? r : 0;
        }
    }
}

// ---------------- weight swizzle fp32 -> bf16 MFMA B-fragments ----------------
__global__ void k_swz_f32(const float* __restrict__ W, u16* __restrict__ dst, int N, int KT){
    int t = blockIdx.x * 256 + threadIdx.x;
    int j = t & 7, lane = (t >> 3) & 63, tile = t >> 9;
    int ktile = tile % KT, ntile = tile / KT;
    int k = ktile * 32 + ((lane >> 4) << 3) + j;
    int n = ntile * 16 + (lane & 15);
    dst[t] = f2b(W[k * N + n]);
}

__global__ void k_swz_pair_f32(const float* __restrict__ A, const float* __restrict__ B, u16* __restrict__ dst,
                               int halfK, int N, int KT){
    int t = blockIdx.x * 256 + threadIdx.x;
    int j = t & 7, lane = (t >> 3) & 63, tile = t >> 9;
    int ktile = tile % KT, ntile = tile / KT;
    int k = ktile * 32 + ((lane >> 4) << 3) + j;
    int n = ntile * 16 + (lane & 15);
    dst[t] = f2b((k < halfK) ? A[k * N + n] : B[(k - halfK) * N + n]);
}

// ---------------- SAGE layer 1 (din=3): fp32 math, bf16 output ----------------
__global__ void k_layer1(const float* __restrict__ x, const int* __restrict__ offs, const int* __restrict__ srcs,
                         const float* __restrict__ invd, const float* __restrict__ Wl, const float* __restrict__ bl,
                         const float* __restrict__ Wr, u16* __restrict__ h1){
    int node = blockIdx.x * 4 + (threadIdx.x >> 6);
    int lane = threadIdx.x & 63;
    int st = offs[node], en = offs[node + 1];
    float s0 = 0.f, s1 = 0.f, s2 = 0.f;
    for (int j = st + lane; j < en; j += 64){
        int s = srcs[j];
        s0 += x[s * 3 + 0]; s1 += x[s * 3 + 1]; s2 += x[s * 3 + 2];
    }
    #pragma unroll
    for (int d = 1; d < 64; d <<= 1){
        s0 += __shfl_xor(s0, d); s1 += __shfl_xor(s1, d); s2 += __shfl_xor(s2, d);
    }
    float inv = invd[node];
    float a0 = s0 * inv, a1 = s1 * inv, a2 = s2 * inv;
    float xi0 = x[node * 3 + 0], xi1 = x[node * 3 + 1], xi2 = x[node * 3 + 2];
    int f0 = lane * 4;
    ushort4 stv;
    u16* sp = (u16*)&stv;
    #pragma unroll
    for (int r = 0; r < 4; r++){
        int n = f0 + r;
        float o = a0 * Wl[n] + a1 * Wl[256 + n] + a2 * Wl[512 + n]
                + xi0 * Wr[n] + xi1 * Wr[256 + n] + xi2 * Wr[512 + n] + bl[n];
        sp[r] = f2b(o > 0.f ? o : 0.f);
    }
    *(ushort4*)(h1 + node * 256 + f0) = stv;
}

// ---------------- fused node layer: aggr(->LDS) + MFMA GEMM [agg|h]@Bs + bias, relu ----------------
// 512 threads, 64 nodes/block, grid 313. B staged through LDS with register prefetch.
__global__ __launch_bounds__(512) void k_layer23(const u16* __restrict__ hin, const int* __restrict__ offs,
    const int* __restrict__ srcs, const float* __restrict__ invd,
    const u16* __restrict__ Bs, const float* __restrict__ bias, u16* __restrict__ hout){
    __shared__ __align__(16) u16 aggA[16384];  // 32 KB: 64 nodes x 256, 16B-block xor swizzle (^row&7)
    __shared__ __align__(16) u16 ldsB[8192];   // 16 KB: B chunk for one k32 (16 ntiles)
    int t = threadIdx.x, wave = t >> 6, lane = t & 63;
    int m0 = blockIdx.x * 64;

    // ---- phase 1: mean-aggregate 8 nodes per wave into aggA ----
    int half = lane >> 5;          // 2 CSR rows in flight
    int cg = lane & 31;            // 16B column group
    for (int i = 0; i < 8; i++){
        int nl = wave * 8 + i;
        int node = m0 + nl;
        int nodec = node < NN ? node : NN - 1;
        int st = offs[nodec], en = offs[nodec + 1];
        float a0=0.f,a1=0.f,a2=0.f,a3=0.f,a4=0.f,a5=0.f,a6=0.f,a7=0.f;
        for (int j = st + half; j < en; j += 2){
            int s = srcs[j];
            uint4 v = *(const uint4*)(hin + s * 256 + cg * 8);
            a0 += b2f((u16)v.x); a1 += b2f((u16)(v.x >> 16));
            a2 += b2f((u16)v.y); a3 += b2f((u16)(v.y >> 16));
            a4 += b2f((u16)v.z); a5 += b2f((u16)(v.z >> 16));
            a6 += b2f((u16)v.w); a7 += b2f((u16)(v.w >> 16));
        }
        a0 += __shfl_xor(a0, 32); a1 += __shfl_xor(a1, 32);
        a2 += __shfl_xor(a2, 32); a3 += __shfl_xor(a3, 32);
        a4 += __shfl_xor(a4, 32); a5 += __shfl_xor(a5, 32);
        a6 += __shfl_xor(a6, 32); a7 += __shfl_xor(a7, 32);
        if (half == 0){
            float inv = invd[nodec];
            uint4 o;
            o.x = (u32)f2b(a0 * inv) | ((u32)f2b(a1 * inv) << 16);
            o.y = (u32)f2b(a2 * inv) | ((u32)f2b(a3 * inv) << 16);
            o.z = (u32)f2b(a4 * inv) | ((u32)f2b(a5 * inv) << 16);
            o.w = (u32)f2b(a6 * inv) | ((u32)f2b(a7 * inv) << 16);
            *(uint4*)(&aggA[nl * 256 + ((cg ^ (nl & 7)) << 3)]) = o;
        }
    }
    __syncthreads();

    // ---- phase 2: GEMM, Mg=4 x Ng=2 wave tiling ----
    int wm = wave & 3, wn = wave >> 2;
    int ml = lane & 15, g = lane >> 4;
    int lrow = wm * 16 + ml;
    int arow = m0 + lrow; if (arow > NN - 1) arow = NN - 1;
    const u16* ph = hin + arow * 256;
    int idx0 = t * 8, idx1 = (512 + t) * 8;
    int nt0 = idx0 >> 9, off0 = idx0 & 511;
    int nt1 = idx1 >> 9, off1 = idx1 & 511;
    uint4 p0 = *(const uint4*)(Bs + (nt0 * 16 + 0) * 512 + off0);
    uint4 p1 = *(const uint4*)(Bs + (nt1 * 16 + 0) * 512 + off1);
    f32x4 acc[8] = {};
    for (int k32 = 0; k32 < 16; k32++){
        __syncthreads();
        *(uint4*)(&ldsB[nt0 * 512 + off0]) = p0;
        *(uint4*)(&ldsB[nt1 * 512 + off1]) = p1;
        if (k32 < 15){
            p0 = *(const uint4*)(Bs + (nt0 * 16 + k32 + 1) * 512 + off0);
            p1 = *(const uint4*)(Bs + (nt1 * 16 + k32 + 1) * 512 + off1);
        }
        __syncthreads();
        bf16x8 af;
        if (k32 < 8)
            af = __builtin_bit_cast(bf16x8, *(const uint4*)(&aggA[lrow * 256 + (((k32 * 4 + g) ^ (lrow & 7)) << 3)]));
        else
            af = __builtin_bit_cast(bf16x8, *(const uint4*)(ph + (k32 - 8) * 32 + g * 8));
        #pragma unroll
        for (int nt = 0; nt < 8; nt++){
            int ntg = wn * 8 + nt;
            bf16x8 bfr = __builtin_bit_cast(bf16x8, *(const uint4*)(&ldsB[ntg * 512 + lane * 8]));
            acc[nt] = __builtin_amdgcn_mfma_f32_16x16x32_bf16(af, bfr, acc[nt], 0, 0, 0);
        }
    }
    #pragma unroll
    for (int nt = 0; nt < 8; nt++){
        int n = wn * 128 + nt * 16 + ml;
        float bn = bias[n];
        #pragma unroll
        for (int r = 0; r < 4; r++){
            int rowg = m0 + wm * 16 + g * 4 + r;
            if (rowg < NN){
                float v = acc[nt][r] + bn;
                hout[rowg * 256 + n] = f2b(v > 0.f ? v : 0.f);
            }
        }
    }
}

// ---------------- bf16-MFMA edge MLP: 512 threads, 128 edges/block, staged B w/ prefetch ----------------
__global__ __launch_bounds__(512) void k_mlp_bf16(const u16* __restrict__ h3b, const int* __restrict__ rowp,
    const int* __restrict__ colp, const float* __restrict__ ea, const float* __restrict__ tdp,
    const u16* __restrict__ B1s, const float* __restrict__ W1tail, const float* __restrict__ b1,
    const u16* __restrict__ B2s, const float* __restrict__ b2v,
    const float* __restrict__ W3, const float* __restrict__ b3, float* __restrict__ out){
    __shared__ __align__(16) u16 ldsX[8192];    // 16 KB: one-k32 B fragment chunk
    __shared__ __align__(16) u16 ldsZ[32768];   // 64 KB: z1, 8 KB per wave, xor-swizzled
    int t = threadIdx.x, wave = t >> 6, lane = t & 63;
    int m0 = blockIdx.x * 128;
    int ml = lane & 15, g = lane >> 4;
    int zbase = wave * 4096;
    int eA = m0 + wave * 16 + ml; if (eA > NE - 1) eA = NE - 1;
    const u16* pr = h3b + rowp[eA] * 256;
    const u16* pc = h3b + colp[eA] * 256;
    float td = tdp[0];

    int idx0 = t * 8, idx1 = (512 + t) * 8;
    int nt0 = idx0 >> 9, off0 = idx0 & 511;
    int nt1 = idx1 >> 9, off1 = idx1 & 511;

    // ---- GEMM1: z1 = relu(feat[:,0:512] @ W1[0:512] + b1 + ea*W1[512] + td*W1[513]) ----
    f32x4 acc[16] = {};
    {
        uint4 p0 = *(const uint4*)(B1s + (nt0 * 16 + 0) * 512 + off0);
        uint4 p1 = *(const uint4*)(B1s + (nt1 * 16 + 0) * 512 + off1);
        for (int kc = 0; kc < 16; kc++){
            __syncthreads();
            *(uint4*)(&ldsX[nt0 * 512 + off0]) = p0;
            *(uint4*)(&ldsX[nt1 * 512 + off1]) = p1;
            if (kc < 15){
                p0 = *(const uint4*)(B1s + (nt0 * 16 + kc + 1) * 512 + off0);
                p1 = *(const uint4*)(B1s + (nt1 * 16 + kc + 1) * 512 + off1);
            }
            __syncthreads();
            const u16* asrc = (kc < 8) ? (pr + kc * 32) : (pc + (kc - 8) * 32);
            bf16x8 af = __builtin_bit_cast(bf16x8, *(const uint4*)(asrc + g * 8));
            #pragma unroll
            for (int nt = 0; nt < 16; nt++){
                bf16x8 bfr = __builtin_bit_cast(bf16x8, *(const uint4*)(&ldsX[(nt * 64 + lane) * 8]));
                acc[nt] = __builtin_amdgcn_mfma_f32_16x16x32_bf16(af, bfr, acc[nt], 0, 0, 0);
            }
        }
    }
    float eav[4];
    #pragma unroll
    for (int r = 0; r < 4; r++){
        int e = m0 + wave * 16 + g * 4 + r; if (e > NE - 1) e = NE - 1;
        eav[r] = ea[e];
    }
    #pragma unroll
    for (int nt = 0; nt < 16; nt++){
        int n = nt * 16 + ml;
        float add0 = b1[n] + td * W1tail[256 + n];
        float w512 = W1tail[n];
        #pragma unroll
        for (int r = 0; r < 4; r++){
            int row = g * 4 + r;    // local row within wave
            float v = acc[nt][r] + add0 + eav[r] * w512;
            v = v > 0.f ? v : 0.f;
            int idx = zbase + row * 256 + ((((n >> 3) ^ (row & 7)) << 3) | (n & 7));
            ldsZ[idx] = f2b(v);
        }
    }
    // ---- GEMM2: z2 = relu(z1 @ W2 + b2), K=256, N=128 ----
    f32x4 acc2[8] = {};
    {
        uint4 q0 = *(const uint4*)(B2s + (nt0 * 8 + 0) * 512 + off0);
        for (int kc = 0; kc < 8; kc++){
            __syncthreads();
            *(uint4*)(&ldsX[nt0 * 512 + off0]) = q0;
            if (kc < 7)
                q0 = *(const uint4*)(B2s + (nt0 * 8 + kc + 1) * 512 + off0);
            __syncthreads();
            int kb = kc * 4 + g;
            bf16x8 af = __builtin_bit_cast(bf16x8, *(const uint4*)(&ldsZ[zbase + ml * 256 + ((kb ^ (ml & 7)) << 3)]));
            #pragma unroll
            for (int nt = 0; nt < 8; nt++){
                bf16x8 bfr = __builtin_bit_cast(bf16x8, *(const uint4*)(&ldsX[(nt * 64 + lane) * 8]));
                acc2[nt] = __builtin_amdgcn_mfma_f32_16x16x32_bf16(af, bfr, acc2[nt], 0, 0, 0);
            }
        }
    }
    // ---- final: bias + relu + dot(W3) in registers (C-layout), fp32 ----
    float s0 = 0.f, s1 = 0.f, s2 = 0.f, s3 = 0.f;
    #pragma unroll
    for (int nt = 0; nt < 8; nt++){
        int n = nt * 16 + ml;
        float bn = b2v[n];
        float w3 = W3[n];
        float z;
        z = acc2[nt][0] + bn; s0 += (z > 0.f ? z : 0.f) * w3;
        z = acc2[nt][1] + bn; s1 += (z > 0.f ? z : 0.f) * w3;
        z = acc2[nt][2] + bn; s2 += (z > 0.f ? z : 0.f) * w3;
        z = acc2[nt][3] + bn; s3 += (z > 0.f ? z : 0.f) * w3;
    }
    #pragma unroll
    for (int d = 1; d < 16; d <<= 1){
        s0 += __shfl_xor(s0, d); s1 += __shfl_xor(s1, d);
        s2 += __shfl_xor(s2, d); s3 += __shfl_xor(s3, d);
    }
    if (ml == 0){
        float bb = b3[0];
        int eb = m0 + wave * 16 + g * 4;
        if (eb + 0 < NE) out[eb + 0] = s0 + bb;
        if (eb + 1 < NE) out[eb + 1] = s1 + bb;
        if (eb + 2 < NE) out[eb + 2] = s2 + bb;
        if (eb + 3 < NE) out[eb + 3] = s3 + bb;
    }
}

__global__ void k_fillcode_f32(float* __restrict__ out, float c){
    int i = blockIdx.x * 256 + threadIdx.x;
    if (i < NE) out[i] = c;
}

extern "C" void kernel_launch(void* const* d_in, const int* in_sizes, int n_in,
                              void* d_out, int out_size, void* d_ws, size_t ws_size,
                              hipStream_t stream){
    float* out = (float*)d_out;

    static const int exp_sizes[19] = {60000,600000,300000,1,768,256,768,65536,256,65536,
                                      65536,256,65536,131584,256,32768,128,128,1};
    int bad = -1;
    if (n_in != 19) bad = 19;
    else for (int k = 0; k < 19; k++) if (in_sizes[k] != exp_sizes[k]){ bad = k; break; }
    if (bad >= 0){
        k_fillcode_f32<<<(NE + 255) / 256, 256, 0, stream>>>(out, 1000.f + 50.f * bad);
        return;
    }

    char* ws = (char*)d_ws;
    size_t off = 0;
    auto alloc = [&](size_t bytes) -> void* {
        void* p = ws + off;
        off += (bytes + 255) & ~(size_t)255;
        return p;
    };
    int*   deg   = (int*)alloc(NN * 4);
    int*   cur   = (int*)alloc(NN * 4);
    int*   offs  = (int*)alloc((NN + 1) * 4);
    float* invd  = (float*)alloc(NN * 4);
    int*   srcs  = (int*)alloc(NE * 4);
    u16*   h1b   = (u16*)alloc((size_t)NN * 256 * 2);
    u16*   h2b   = (u16*)alloc((size_t)NN * 256 * 2);
    u16*   h3b   = (u16*)alloc((size_t)NN * 256 * 2);
    u16*   WLs2  = (u16*)alloc(512 * 256 * 2);
    u16*   WLs3  = (u16*)alloc(512 * 256 * 2);
    u16*   B1s   = (u16*)alloc(512 * 256 * 2);
    u16*   B2s   = (u16*)alloc(256 * 128 * 2);
    if (off > ws_size){
        k_fillcode_f32<<<(NE + 255) / 256, 256, 0, stream>>>(out, 9000.f);
        return;
    }

    const float* x   = (const float*)d_in[0];
    const int*   ei  = (const int*)d_in[1];     // (2,E) int32: [row..., col...]
    const float* ea  = (const float*)d_in[2];
    const float* td  = (const float*)d_in[3];
    const float* Wl1 = (const float*)d_in[4];
    const float* bl1 = (const float*)d_in[5];
    const float* Wr1 = (const float*)d_in[6];
    const float* Wl2 = (const float*)d_in[7];
    const float* bl2 = (const float*)d_in[8];
    const float* Wr2 = (const float*)d_in[9];
    const float* Wl3 = (const float*)d_in[10];
    const float* bl3 = (const float*)d_in[11];
    const float* Wr3 = (const float*)d_in[12];
    const float* W1  = (const float*)d_in[13];
    const float* b1  = (const float*)d_in[14];
    const float* W2  = (const float*)d_in[15];
    const float* b2  = (const float*)d_in[16];
    const float* W3  = (const float*)d_in[17];
    const float* b3  = (const float*)d_in[18];

    hipMemsetAsync(deg, 0, (size_t)((char*)cur - (char*)deg) + NN * 4, stream);

    const int* rowv = ei;          // sources
    const int* colv = ei + NE;     // targets

    k_count<<<(NE + 255) / 256, 256, 0, stream>>>(colv, deg);
    k_scan <<<1, 1024, 0, stream>>>(deg, offs, invd);
    k_fill <<<(NE + 255) / 256, 256, 0, stream>>>(rowv, colv, offs, cur, srcs);

    // weight fragment prep
    k_swz_pair_f32<<<512, 256, 0, stream>>>(Wl2, Wr2, WLs2, 256, 256, 16);
    k_swz_pair_f32<<<512, 256, 0, stream>>>(Wl3, Wr3, WLs3, 256, 256, 16);
    k_swz_f32<<<512, 256, 0, stream>>>(W1, B1s, 256, 16);
    k_swz_f32<<<128, 256, 0, stream>>>(W2, B2s, 128, 8);

    // SAGE layer 1 (fp32 math, bf16 out)
    k_layer1<<<NN / 4, 256, 0, stream>>>(x, offs, srcs, invd, Wl1, bl1, Wr1, h1b);

    // SAGE layers 2,3: fused aggr + MFMA GEMM
    k_layer23<<<(NN + 63) / 64, 512, 0, stream>>>(h1b, offs, srcs, invd, WLs2, bl2, h2b);
    k_layer23<<<(NN + 63) / 64, 512, 0, stream>>>(h2b, offs, srcs, invd, WLs3, bl3, h3b);

    // fused edge MLP, bf16 MFMA
    k_mlp_bf16<<<(NE + 127) / 128, 512, 0, stream>>>(h3b, rowv, colv, ea, td,
                                                     B1s, W1 + 512 * 256, b1, B2s, b2, W3, b3, out);
}

// Round 13
// 394.793 us; speedup vs baseline: 1.1281x; 1.1281x over previous
//
#include <hip/hip_runtime.h>

#define NN 20000
#define NE 300000

typedef unsigned short u16;
typedef unsigned int   u32;

typedef __bf16 bf16x8 __attribute__((ext_vector_type(8)));
typedef float  f32x4  __attribute__((ext_vector_type(4)));

__device__ __forceinline__ float b2f(u16 u){ u32 x = ((u32)u) << 16; return __builtin_bit_cast(float, x); }
__device__ __forceinline__ u16 f2b(float f){
    u32 x = __builtin_bit_cast(u32, f);
    u32 r = x + 0x7fffu + ((x >> 16) & 1u);
    return (u16)(r >> 16);
}

// ---------------- CSR build: bucket edges by col (target), store row (source) ----------------
__global__ void k_count(const int* __restrict__ key, int* __restrict__ deg){
    int e = blockIdx.x * 256 + threadIdx.x;
    if (e < NE){
        int c = key[e];
        if (c >= 0 && c < NN) atomicAdd(&deg[c], 1);
    }
}

__global__ void k_scan(const int* __restrict__ deg, int* __restrict__ offs, float* __restrict__ invd){
    __shared__ int part[1024];
    int t = threadIdx.x;
    int base = t * 20;
    int s = 0;
    for (int i = 0; i < 20; i++){ int idx = base + i; if (idx < NN) s += deg[idx]; }
    part[t] = s; __syncthreads();
    for (int d = 1; d < 1024; d <<= 1){
        int v = (t >= d) ? part[t - d] : 0;
        __syncthreads();
        part[t] += v;
        __syncthreads();
    }
    int run = part[t] - s;
    for (int i = 0; i < 20; i++){
        int idx = base + i;
        if (idx < NN){
            offs[idx] = run;
            int d0 = deg[idx];
            run += d0;
            invd[idx] = 1.0f / (float)(d0 > 0 ? d0 : 1);
        }
    }
    if (t == 1023) offs[NN] = part[1023];
}

__global__ void k_fill(const int* __restrict__ val, const int* __restrict__ key,
                       const int* __restrict__ offs, int* __restrict__ cur, int* __restrict__ srcs){
    int e = blockIdx.x * 256 + threadIdx.x;
    if (e < NE){
        int c = key[e];
        if (c >= 0 && c < NN){
            int slot = offs[c] + atomicAdd(&cur[c], 1);
            int r = val[e];
            srcs[slot] = (r >= 0 && r < NN) ? r : 0;
        }
    }
}

// ---------------- weight swizzle fp32 -> bf16 MFMA B-fragments ----------------
__global__ void k_swz_f32(const float* __restrict__ W, u16* __restrict__ dst, int N, int KT){
    int t = blockIdx.x * 256 + threadIdx.x;
    int j = t & 7, lane = (t >> 3) & 63, tile = t >> 9;
    int ktile = tile % KT, ntile = tile / KT;
    int k = ktile * 32 + ((lane >> 4) << 3) + j;
    int n = ntile * 16 + (lane & 15);
    dst[t] = f2b(W[k * N + n]);
}

__global__ void k_swz_pair_f32(const float* __restrict__ A, const float* __restrict__ B, u16* __restrict__ dst,
                               int halfK, int N, int KT){
    int t = blockIdx.x * 256 + threadIdx.x;
    int j = t & 7, lane = (t >> 3) & 63, tile = t >> 9;
    int ktile = tile % KT, ntile = tile / KT;
    int k = ktile * 32 + ((lane >> 4) << 3) + j;
    int n = ntile * 16 + (lane & 15);
    dst[t] = f2b((k < halfK) ? A[k * N + n] : B[(k - halfK) * N + n]);
}

// ---------------- SAGE layer 1 (din=3): fp32 math, bf16 output ----------------
__global__ void k_layer1(const float* __restrict__ x, const int* __restrict__ offs, const int* __restrict__ srcs,
                         const float* __restrict__ invd, const float* __restrict__ Wl, const float* __restrict__ bl,
                         const float* __restrict__ Wr, u16* __restrict__ h1){
    int node = blockIdx.x * 4 + (threadIdx.x >> 6);
    int lane = threadIdx.x & 63;
    int st = offs[node], en = offs[node + 1];
    float s0 = 0.f, s1 = 0.f, s2 = 0.f;
    for (int j = st + lane; j < en; j += 64){
        int s = srcs[j];
        s0 += x[s * 3 + 0]; s1 += x[s * 3 + 1]; s2 += x[s * 3 + 2];
    }
    #pragma unroll
    for (int d = 1; d < 64; d <<= 1){
        s0 += __shfl_xor(s0, d); s1 += __shfl_xor(s1, d); s2 += __shfl_xor(s2, d);
    }
    float inv = invd[node];
    float a0 = s0 * inv, a1 = s1 * inv, a2 = s2 * inv;
    float xi0 = x[node * 3 + 0], xi1 = x[node * 3 + 1], xi2 = x[node * 3 + 2];
    int f0 = lane * 4;
    ushort4 stv;
    u16* sp = (u16*)&stv;
    #pragma unroll
    for (int r = 0; r < 4; r++){
        int n = f0 + r;
        float o = a0 * Wl[n] + a1 * Wl[256 + n] + a2 * Wl[512 + n]
                + xi0 * Wr[n] + xi1 * Wr[256 + n] + xi2 * Wr[512 + n] + bl[n];
        sp[r] = f2b(o > 0.f ? o : 0.f);
    }
    *(ushort4*)(h1 + node * 256 + f0) = stv;
}

// ---------------- mean aggregation over CSR: 16B/lane, 2 rows in flight per wave ----------------
__global__ void k_aggr(const u16* __restrict__ hin, const int* __restrict__ offs, const int* __restrict__ srcs,
                       const float* __restrict__ invd, u16* __restrict__ aggr){
    int node = blockIdx.x * 4 + (threadIdx.x >> 6);
    int lane = threadIdx.x & 63;
    int st = offs[node], en = offs[node + 1];
    int half = lane >> 5;
    int c0 = (lane & 31) * 8;
    float a0=0.f,a1=0.f,a2=0.f,a3=0.f,a4=0.f,a5=0.f,a6=0.f,a7=0.f;
    for (int j = st + half; j < en; j += 2){
        int s = srcs[j];
        uint4 v = *(const uint4*)(hin + s * 256 + c0);
        a0 += b2f((u16)v.x); a1 += b2f((u16)(v.x >> 16));
        a2 += b2f((u16)v.y); a3 += b2f((u16)(v.y >> 16));
        a4 += b2f((u16)v.z); a5 += b2f((u16)(v.z >> 16));
        a6 += b2f((u16)v.w); a7 += b2f((u16)(v.w >> 16));
    }
    a0 += __shfl_xor(a0, 32); a1 += __shfl_xor(a1, 32);
    a2 += __shfl_xor(a2, 32); a3 += __shfl_xor(a3, 32);
    a4 += __shfl_xor(a4, 32); a5 += __shfl_xor(a5, 32);
    a6 += __shfl_xor(a6, 32); a7 += __shfl_xor(a7, 32);
    if (half == 0){
        float inv = invd[node];
        uint4 o;
        o.x = (u32)f2b(a0 * inv) | ((u32)f2b(a1 * inv) << 16);
        o.y = (u32)f2b(a2 * inv) | ((u32)f2b(a3 * inv) << 16);
        o.z = (u32)f2b(a4 * inv) | ((u32)f2b(a5 * inv) << 16);
        o.w = (u32)f2b(a6 * inv) | ((u32)f2b(a7 * inv) << 16);
        *(uint4*)(aggr + node * 256 + c0) = o;
    }
}

// ---------------- node dense layer: relu([aggr|hin] @ Bs + bias), MFMA, N-split grid ----------------
// grid (313, 2): block computes 64 rows x 128 cols. B staged through 8 KB LDS w/ register prefetch.
__global__ __launch_bounds__(256) void k_gemm_node(const u16* __restrict__ aggr, const u16* __restrict__ hin,
    const u16* __restrict__ Bs, const float* __restrict__ bias, u16* __restrict__ out){
    __shared__ __align__(16) u16 ldsB[4096];   // 8 KB: one k32-chunk, 8 local ntiles
    int t = threadIdx.x, wave = t >> 6, lane = t & 63;
    int m0 = blockIdx.x * 64 + wave * 16;
    int nb = blockIdx.y * 8;                   // global ntile base (8 ntiles = 128 cols)
    int ml = lane & 15, g = lane >> 4;
    int arow = m0 + ml; if (arow > NN - 1) arow = NN - 1;
    const u16* pa = aggr + arow * 256;
    const u16* ph = hin  + arow * 256;

    int flat0 = t * 8, flat1 = (256 + t) * 8;
    int s0i = flat0 >> 9, o0 = flat0 & 511;    // local ntile 0..3
    int s1i = flat1 >> 9, o1 = flat1 & 511;    // local ntile 4..7
    uint4 p0 = *(const uint4*)(Bs + ((nb + s0i) * 16 + 0) * 512 + o0);
    uint4 p1 = *(const uint4*)(Bs + ((nb + s1i) * 16 + 0) * 512 + o1);

    f32x4 acc[8] = {};
    for (int k32 = 0; k32 < 16; k32++){
        __syncthreads();
        *(uint4*)(&ldsB[s0i * 512 + o0]) = p0;
        *(uint4*)(&ldsB[s1i * 512 + o1]) = p1;
        if (k32 < 15){
            p0 = *(const uint4*)(Bs + ((nb + s0i) * 16 + k32 + 1) * 512 + o0);
            p1 = *(const uint4*)(Bs + ((nb + s1i) * 16 + k32 + 1) * 512 + o1);
        }
        __syncthreads();
        const u16* asrc = (k32 < 8) ? (pa + k32 * 32) : (ph + (k32 - 8) * 32);
        bf16x8 af = __builtin_bit_cast(bf16x8, *(const uint4*)(asrc + g * 8));
        #pragma unroll
        for (int nt = 0; nt < 8; nt++){
            bf16x8 bfr = __builtin_bit_cast(bf16x8, *(const uint4*)(&ldsB[(nt * 64 + lane) * 8]));
            acc[nt] = __builtin_amdgcn_mfma_f32_16x16x32_bf16(af, bfr, acc[nt], 0, 0, 0);
        }
    }
    #pragma unroll
    for (int nt = 0; nt < 8; nt++){
        int n = (nb + nt) * 16 + ml;
        float bn = bias[n];
        #pragma unroll
        for (int r = 0; r < 4; r++){
            int rowg = m0 + g * 4 + r;
            if (rowg < NN){
                float v = acc[nt][r] + bn;
                out[rowg * 256 + n] = f2b(v > 0.f ? v : 0.f);
            }
        }
    }
}

// ---------------- bf16-MFMA edge MLP: 512 threads, 128 edges/block, staged B w/ prefetch ----------------
__global__ __launch_bounds__(512) void k_mlp_bf16(const u16* __restrict__ h3b, const int* __restrict__ rowp,
    const int* __restrict__ colp, const float* __restrict__ ea, const float* __restrict__ tdp,
    const u16* __restrict__ B1s, const float* __restrict__ W1tail, const float* __restrict__ b1,
    const u16* __restrict__ B2s, const float* __restrict__ b2v,
    const float* __restrict__ W3, const float* __restrict__ b3, float* __restrict__ out){
    __shared__ __align__(16) u16 ldsX[8192];    // 16 KB: one-k32 B fragment chunk
    __shared__ __align__(16) u16 ldsZ[32768];   // 64 KB: z1, 8 KB per wave, xor-swizzled
    int t = threadIdx.x, wave = t >> 6, lane = t & 63;
    int m0 = blockIdx.x * 128;
    int ml = lane & 15, g = lane >> 4;
    int zbase = wave * 4096;
    int eA = m0 + wave * 16 + ml; if (eA > NE - 1) eA = NE - 1;
    const u16* pr = h3b + rowp[eA] * 256;
    const u16* pc = h3b + colp[eA] * 256;
    float td = tdp[0];

    int idx0 = t * 8, idx1 = (512 + t) * 8;
    int nt0 = idx0 >> 9, off0 = idx0 & 511;
    int nt1 = idx1 >> 9, off1 = idx1 & 511;

    f32x4 acc[16] = {};
    {
        uint4 p0 = *(const uint4*)(B1s + (nt0 * 16 + 0) * 512 + off0);
        uint4 p1 = *(const uint4*)(B1s + (nt1 * 16 + 0) * 512 + off1);
        for (int kc = 0; kc < 16; kc++){
            __syncthreads();
            *(uint4*)(&ldsX[nt0 * 512 + off0]) = p0;
            *(uint4*)(&ldsX[nt1 * 512 + off1]) = p1;
            if (kc < 15){
                p0 = *(const uint4*)(B1s + (nt0 * 16 + kc + 1) * 512 + off0);
                p1 = *(const uint4*)(B1s + (nt1 * 16 + kc + 1) * 512 + off1);
            }
            __syncthreads();
            const u16* asrc = (kc < 8) ? (pr + kc * 32) : (pc + (kc - 8) * 32);
            bf16x8 af = __builtin_bit_cast(bf16x8, *(const uint4*)(asrc + g * 8));
            #pragma unroll
            for (int nt = 0; nt < 16; nt++){
                bf16x8 bfr = __builtin_bit_cast(bf16x8, *(const uint4*)(&ldsX[(nt * 64 + lane) * 8]));
                acc[nt] = __builtin_amdgcn_mfma_f32_16x16x32_bf16(af, bfr, acc[nt], 0, 0, 0);
            }
        }
    }
    float eav[4];
    #pragma unroll
    for (int r = 0; r < 4; r++){
        int e = m0 + wave * 16 + g * 4 + r; if (e > NE - 1) e = NE - 1;
        eav[r] = ea[e];
    }
    #pragma unroll
    for (int nt = 0; nt < 16; nt++){
        int n = nt * 16 + ml;
        float add0 = b1[n] + td * W1tail[256 + n];
        float w512 = W1tail[n];
        #pragma unroll
        for (int r = 0; r < 4; r++){
            int row = g * 4 + r;
            float v = acc[nt][r] + add0 + eav[r] * w512;
            v = v > 0.f ? v : 0.f;
            int idx = zbase + row * 256 + ((((n >> 3) ^ (row & 7)) << 3) | (n & 7));
            ldsZ[idx] = f2b(v);
        }
    }
    f32x4 acc2[8] = {};
    {
        uint4 q0 = *(const uint4*)(B2s + (nt0 * 8 + 0) * 512 + off0);
        for (int kc = 0; kc < 8; kc++){
            __syncthreads();
            *(uint4*)(&ldsX[nt0 * 512 + off0]) = q0;
            if (kc < 7)
                q0 = *(const uint4*)(B2s + (nt0 * 8 + kc + 1) * 512 + off0);
            __syncthreads();
            int kb = kc * 4 + g;
            bf16x8 af = __builtin_bit_cast(bf16x8, *(const uint4*)(&ldsZ[zbase + ml * 256 + ((kb ^ (ml & 7)) << 3)]));
            #pragma unroll
            for (int nt = 0; nt < 8; nt++){
                bf16x8 bfr = __builtin_bit_cast(bf16x8, *(const uint4*)(&ldsX[(nt * 64 + lane) * 8]));
                acc2[nt] = __builtin_amdgcn_mfma_f32_16x16x32_bf16(af, bfr, acc2[nt], 0, 0, 0);
            }
        }
    }
    float s0 = 0.f, s1 = 0.f, s2 = 0.f, s3 = 0.f;
    #pragma unroll
    for (int nt = 0; nt < 8; nt++){
        int n = nt * 16 + ml;
        float bn = b2v[n];
        float w3 = W3[n];
        float z;
        z = acc2[nt][0] + bn; s0 += (z > 0.f ? z : 0.f) * w3;
        z = acc2[nt][1] + bn; s1 += (z > 0.f ? z : 0.f) * w3;
        z = acc2[nt][2] + bn; s2 += (z > 0.f ? z : 0.f) * w3;
        z = acc2[nt][3] + bn; s3 += (z > 0.f ? z : 0.f) * w3;
    }
    #pragma unroll
    for (int d = 1; d < 16; d <<= 1){
        s0 += __shfl_xor(s0, d); s1 += __shfl_xor(s1, d);
        s2 += __shfl_xor(s2, d); s3 += __shfl_xor(s3, d);
    }
    if (ml == 0){
        float bb = b3[0];
        int eb = m0 + wave * 16 + g * 4;
        if (eb + 0 < NE) out[eb + 0] = s0 + bb;
        if (eb + 1 < NE) out[eb + 1] = s1 + bb;
        if (eb + 2 < NE) out[eb + 2] = s2 + bb;
        if (eb + 3 < NE) out[eb + 3] = s3 + bb;
    }
}

__global__ void k_fillcode_f32(float* __restrict__ out, float c){
    int i = blockIdx.x * 256 + threadIdx.x;
    if (i < NE) out[i] = c;
}

extern "C" void kernel_launch(void* const* d_in, const int* in_sizes, int n_in,
                              void* d_out, int out_size, void* d_ws, size_t ws_size,
                              hipStream_t stream){
    float* out = (float*)d_out;

    static const int exp_sizes[19] = {60000,600000,300000,1,768,256,768,65536,256,65536,
                                      65536,256,65536,131584,256,32768,128,128,1};
    int bad = -1;
    if (n_in != 19) bad = 19;
    else for (int k = 0; k < 19; k++) if (in_sizes[k] != exp_sizes[k]){ bad = k; break; }
    if (bad >= 0){
        k_fillcode_f32<<<(NE + 255) / 256, 256, 0, stream>>>(out, 1000.f + 50.f * bad);
        return;
    }

    char* ws = (char*)d_ws;
    size_t off = 0;
    auto alloc = [&](size_t bytes) -> void* {
        void* p = ws + off;
        off += (bytes + 255) & ~(size_t)255;
        return p;
    };
    int*   deg   = (int*)alloc(NN * 4);
    int*   cur   = (int*)alloc(NN * 4);
    int*   offs  = (int*)alloc((NN + 1) * 4);
    float* invd  = (float*)alloc(NN * 4);
    int*   srcs  = (int*)alloc(NE * 4);
    u16*   h1b   = (u16*)alloc((size_t)NN * 256 * 2);
    u16*   h2b   = (u16*)alloc((size_t)NN * 256 * 2);
    u16*   h3b   = (u16*)alloc((size_t)NN * 256 * 2);
    u16*   aggb  = (u16*)alloc((size_t)NN * 256 * 2);
    u16*   WLs2  = (u16*)alloc(512 * 256 * 2);
    u16*   WLs3  = (u16*)alloc(512 * 256 * 2);
    u16*   B1s   = (u16*)alloc(512 * 256 * 2);
    u16*   B2s   = (u16*)alloc(256 * 128 * 2);
    if (off > ws_size){
        k_fillcode_f32<<<(NE + 255) / 256, 256, 0, stream>>>(out, 9000.f);
        return;
    }

    const float* x   = (const float*)d_in[0];
    const int*   ei  = (const int*)d_in[1];     // (2,E) int32: [row..., col...]
    const float* ea  = (const float*)d_in[2];
    const float* td  = (const float*)d_in[3];
    const float* Wl1 = (const float*)d_in[4];
    const float* bl1 = (const float*)d_in[5];
    const float* Wr1 = (const float*)d_in[6];
    const float* Wl2 = (const float*)d_in[7];
    const float* bl2 = (const float*)d_in[8];
    const float* Wr2 = (const float*)d_in[9];
    const float* Wl3 = (const float*)d_in[10];
    const float* bl3 = (const float*)d_in[11];
    const float* Wr3 = (const float*)d_in[12];
    const float* W1  = (const float*)d_in[13];
    const float* b1  = (const float*)d_in[14];
    const float* W2  = (const float*)d_in[15];
    const float* b2  = (const float*)d_in[16];
    const float* W3  = (const float*)d_in[17];
    const float* b3  = (const float*)d_in[18];

    hipMemsetAsync(deg, 0, (size_t)((char*)cur - (char*)deg) + NN * 4, stream);

    const int* rowv = ei;          // sources
    const int* colv = ei + NE;     // targets

    k_count<<<(NE + 255) / 256, 256, 0, stream>>>(colv, deg);
    k_scan <<<1, 1024, 0, stream>>>(deg, offs, invd);
    k_fill <<<(NE + 255) / 256, 256, 0, stream>>>(rowv, colv, offs, cur, srcs);

    // weight fragment prep
    k_swz_pair_f32<<<512, 256, 0, stream>>>(Wl2, Wr2, WLs2, 256, 256, 16);
    k_swz_pair_f32<<<512, 256, 0, stream>>>(Wl3, Wr3, WLs3, 256, 256, 16);
    k_swz_f32<<<512, 256, 0, stream>>>(W1, B1s, 256, 16);
    k_swz_f32<<<128, 256, 0, stream>>>(W2, B2s, 128, 8);

    // SAGE layer 1 (fp32 math, bf16 out)
    k_layer1<<<NN / 4, 256, 0, stream>>>(x, offs, srcs, invd, Wl1, bl1, Wr1, h1b);

    dim3 ggrid((NN + 63) / 64, 2);

    // SAGE layers 2,3: separate aggr (high TLP) + N-split staged GEMM
    k_aggr<<<NN / 4, 256, 0, stream>>>(h1b, offs, srcs, invd, aggb);
    k_gemm_node<<<ggrid, 256, 0, stream>>>(aggb, h1b, WLs2, bl2, h2b);

    k_aggr<<<NN / 4, 256, 0, stream>>>(h2b, offs, srcs, invd, aggb);
    k_gemm_node<<<ggrid, 256, 0, stream>>>(aggb, h2b, WLs3, bl3, h3b);

    // fused edge MLP, bf16 MFMA
    k_mlp_bf16<<<(NE + 127) / 128, 512, 0, stream>>>(h3b, rowv, colv, ea, td,
                                                     B1s, W1 + 512 * 256, b1, B2s, b2, W3, b3, out);
}